// Round 7
// baseline (184.813 us; speedup 1.0000x reference)
//
#include <hip/hip_runtime.h>
#include <stdint.h>

// ---------------------------------------------------------------------------
// HardBinaryConv, algebraic form.
//   sign(w) = 1 - 2*[w <= 0]   (reference: 2*(w>0)-1)
//   y[n,o,h,w] = scale[o] * T[n,h,w]
//              - 2*scale[o] * sum_{(i,r,s): w[o,i,r,s]<=0} x[n,i,h+r-1,w+s-1]
//   T[n,h,w]   = sum_{r,s} U[n,h+r-1,w+s-1]   (3x3 box, zero-pad)
//   U[n,h,w]   = sum_i x[n,i,h,w]             (channel sum)
// Correction set is empty for uniform*1e-3 weights but handled exactly.
// Traffic floor: read x (103 MB) + write y (103 MB) ~= 33 us at 6.3 TB/s.
//
// R6 post-mortem: yout was ~29 us (vs 16 BW-bound) because 8192 blocks each
// re-read the full 12.5-KB T[n] plane -> 100 MB of cross-XCD L3 reads
// contending with the store stream. This version: 2 dispatches.
//   stage1U: x -> U[n][3136] (full channel sum; proven load pattern) + wprep.
//   youtbox: 2048 blocks = 32 n x 64 o-groups (4 planes). Per block:
//     U[n] (12.5 KB contiguous) -> LDS, 3x3 box -> Tls in LDS, then
//     4 planes x 56 f32x4 NT stores (50 KB). T traffic /4, boxsum kernel,
//     one bubble and the T round-trip deleted.
// Fusion lessons respected: f32x4 stores (R2), contiguous prelude (R3),
// 4x amortization + 8 blocks/CU queue depth (R5).
// ---------------------------------------------------------------------------

typedef float f32x4 __attribute__((ext_vector_type(4)));

// Stage 1, role A (blocks 0..1567): full 256-channel sums -> U[n][3136].
// Stage 1, role B (blocks 1568..1823): scale[o] = mean|w[o]| + sparse list
// of non-positive weights (block o-1568 owns nneg[o]; no pre-zero needed).
__global__ __launch_bounds__(256) void stage1U(const float* __restrict__ x,
                                               float* __restrict__ U,
                                               const float* __restrict__ w,
                                               float* __restrict__ scale,
                                               int* __restrict__ nneg,
                                               int* __restrict__ negidx) {
    __shared__ float Ls[16][64];             // [g][pixel-float]; f32x4 writes
    __shared__ float red[4];                 // are 2-way bank aliased = free
    __shared__ int cnt;
    const int t = threadIdx.x;
    if (blockIdx.x < 1568) {
        const int b    = blockIdx.x;
        const int n    = b / 49;
        const int tile = b - n * 49;         // 49 tiles * 16 f32x4 = 784
        const int g    = t >> 4;             // 0..15 channel group
        const int sl   = t & 15;             // 0..15 pixel slot
        const int hw4  = tile * 16 + sl;
        const f32x4* xp =
            (const f32x4*)(x + (size_t)(n * 256 + g * 16) * 3136) + hw4;
        f32x4 s = {0.f, 0.f, 0.f, 0.f};
#pragma unroll
        for (int c = 0; c < 16; ++c)         // 784 f32x4 = one 3136-elem plane
            s += __builtin_nontemporal_load(xp + c * 784);
        *(f32x4*)&Ls[g][sl * 4] = s;
        __syncthreads();
        if (t < 64) {                        // column sum over 16 groups
            float us = 0.f;
#pragma unroll
            for (int g2 = 0; g2 < 16; ++g2) us += Ls[g2][t];
            U[(size_t)n * 3136 + tile * 64 + t] = us;  // 256 B coalesced
        }
    } else {
        const int o = blockIdx.x - 1568;
        if (t == 0) cnt = 0;
        __syncthreads();
        const float* wp = w + ((size_t)o * 256 + t) * 9;
        float s = 0.f;
#pragma unroll
        for (int k = 0; k < 9; ++k) {
            const float v = wp[k];
            s += fabsf(v);
            if (v <= 0.f) {                  // sign would be -1 here (rare)
                const int slot = atomicAdd(&cnt, 1);
                negidx[o * 2304 + slot] = t * 9 + k;
            }
        }
#pragma unroll
        for (int off = 32; off > 0; off >>= 1) s += __shfl_down(s, off);
        if ((t & 63) == 0) red[t >> 6] = s;
        __syncthreads();
        if (t == 0) {
            scale[o] = (red[0] + red[1] + red[2] + red[3]) * (1.f / 2304.f);
            nneg[o]  = cnt;
        }
    }
}

// Stage 2: fused {3x3 box on U in LDS + 4-plane broadcast}.
// grid 2048 = 32 n * 64 o-groups (o-group fastest -> U[n] L2/L3-hot).
__global__ __launch_bounds__(256) void youtbox(const float* __restrict__ U,
                                               const float* __restrict__ scale,
                                               const int* __restrict__ nneg,
                                               const int* __restrict__ negidx,
                                               const float* __restrict__ x,
                                               float* __restrict__ out) {
    __shared__ float Us[3136];               // U[n] plane
    __shared__ float Tls[3136];              // box-filtered plane
    __shared__ float ssc[4];
    __shared__ int   snn[4];
    const int b  = blockIdx.x;
    const int og = b & 63;                   // 4 o-planes per block
    const int n  = b >> 6;
    const int t  = threadIdx.x;

    if (t < 4) {                             // stage per-o constants
        ssc[t] = scale[og * 4 + t];
        snn[t] = nneg[og * 4 + t];
    }
    const f32x4* Un4 = (const f32x4*)(U + (size_t)n * 3136);
    f32x4* Us4 = (f32x4*)Us;
#pragma unroll
    for (int j = 0; j < 4; ++j) {
        const int i = t + j * 256;
        if (i < 784) Us4[i] = Un4[i];        // 12.5 KB contiguous
    }
    __syncthreads();
    for (int p = t; p < 3136; p += 256) {    // 3x3 zero-padded box
        const int h = p / 56, w = p - h * 56;
        float acc = 0.f;
#pragma unroll
        for (int r = -1; r <= 1; ++r) {
            const int hh = h + r;
            if (hh < 0 || hh > 55) continue;
            const float* row = Us + hh * 56;
            if (w > 0)  acc += row[w - 1];
            acc += row[w];
            if (w < 55) acc += row[w + 1];
        }
        Tls[p] = acc;
    }
    __syncthreads();

    const f32x4* T4 = (const f32x4*)Tls;
#pragma unroll
    for (int ol = 0; ol < 4; ++ol) {
        const int o = og * 4 + ol;
        const float sc = ssc[ol];
        const int nn = snn[ol];
        f32x4* op = (f32x4*)(out + ((size_t)n * 256 + o) * 3136);
        if (nn == 0) {                       // uniform fast path
#pragma unroll
            for (int j = 0; j < 4; ++j) {
                const int hw4 = t + j * 256;
                if (hw4 >= 784) break;       // 784 f32x4 = 3136 floats
                f32x4 v = T4[hw4] * sc;
                __builtin_nontemporal_store(v, op + hw4);
            }
        } else {                             // exact sparse correction (rare)
            const float c2 = 2.f * sc;
#pragma unroll
            for (int j = 0; j < 4; ++j) {
                const int hw4 = t + j * 256;
                if (hw4 >= 784) break;
                f32x4 v = T4[hw4] * sc;
                for (int q = 0; q < nn; ++q) {
                    const int iof = negidx[o * 2304 + q];
                    const int ic = iof / 9, rs = iof - ic * 9;
                    const int r = rs / 3 - 1, s2 = rs - (rs / 3) * 3 - 1;
                    const float* xpl = x + ((size_t)n * 256 + ic) * 3136;
#pragma unroll
                    for (int e = 0; e < 4; ++e) {
                        const int p = hw4 * 4 + e;
                        const int h = p / 56 + r, ww = p - (p / 56) * 56 + s2;
                        const float xv = (h >= 0 && h < 56 && ww >= 0 && ww < 56)
                                             ? xpl[h * 56 + ww] : 0.f;
                        v[e] -= c2 * xv;
                    }
                }
                __builtin_nontemporal_store(v, op + hw4);
            }
        }
    }
}

// ---------------------------------------------------------------------------
extern "C" void kernel_launch(void* const* d_in, const int* in_sizes, int n_in,
                              void* d_out, int out_size, void* d_ws, size_t ws_size,
                              hipStream_t stream) {
    const float* x = (const float*)d_in[0];   // (32,256,56,56) fp32, 103 MB
    const float* w = (const float*)d_in[1];   // (256,256,3,3) fp32, 2.4 MB
    float* out = (float*)d_out;               // (32,256,56,56) fp32, 103 MB

    char* ws = (char*)d_ws;
    size_t off = 0;
    float* U = (float*)(ws + off);            // 32*3136 fp32 = 401 KB
    off += (size_t)32 * 3136 * 4;
    float* scale = (float*)(ws + off);        // 256 fp32
    off += 256 * 4;
    int* nneg = (int*)(ws + off);             // 256 int
    off += 256 * 4;
    int* negidx = (int*)(ws + off);           // 256*2304 int = 2.4 MB

    stage1U<<<dim3(1824), 256, 0, stream>>>(x, U, w, scale, nneg, negidx);
    youtbox<<<dim3(2048), 256, 0, stream>>>(U, scale, nneg, negidx, x, out);
}